// Round 1
// baseline (462.392 us; speedup 1.0000x reference)
//
#include <hip/hip_runtime.h>

typedef __bf16 bf16x8 __attribute__((ext_vector_type(8)));
typedef float f32x4 __attribute__((ext_vector_type(4)));

__device__ __forceinline__ unsigned short f2bf(float f) {
    union { float f; unsigned int u; } v; v.f = f;
    unsigned int u = v.u;
    unsigned int r = (u + 0x7fffu + ((u >> 16) & 1u)) >> 16;
    return (unsigned short)r;
}

// ---------------------------------------------------------------------------
// Kernel 1: reconstruct TT conv weights -> bf16, MFMA-A-fragment layout.
// kidx = (kh*3+kw)*128 + c ; stored wb[(kidx>>3)*2048 + d*8 + (kidx&7)]
// ---------------------------------------------------------------------------
__global__ void build_w_kernel(const float* __restrict__ core0,
                               const float* __restrict__ core1,
                               const float* __restrict__ core2,
                               unsigned short* __restrict__ wb) {
    __shared__ float s1[96];   // core1[d]: [r][kh][s]
    __shared__ float s2[12];   // core2[d]: [s][kw]
    const int d = blockIdx.x;
    const int c = threadIdx.x;   // 128 threads
    if (c < 96) s1[c] = core1[d * 96 + c];
    if (c >= 96 && c < 108) s2[c - 96] = core2[d * 12 + (c - 96)];
    __syncthreads();
    float t0[8];
#pragma unroll
    for (int r = 0; r < 8; ++r) t0[r] = core0[(d * 128 + c) * 8 + r];
#pragma unroll
    for (int kh = 0; kh < 3; ++kh) {
        float v[4] = {0.f, 0.f, 0.f, 0.f};
#pragma unroll
        for (int r = 0; r < 8; ++r)
#pragma unroll
            for (int s = 0; s < 4; ++s)
                v[s] += t0[r] * s1[(r * 3 + kh) * 4 + s];
#pragma unroll
        for (int kw = 0; kw < 3; ++kw) {
            float val = 0.f;
#pragma unroll
            for (int s = 0; s < 4; ++s) val += v[s] * s2[s * 3 + kw];
            const int kidx = (kh * 3 + kw) * 128 + c;
            wb[(kidx >> 3) * 2048 + d * 8 + (kidx & 7)] = f2bf(val);
        }
    }
}

// ---------------------------------------------------------------------------
// Kernel 2: rolling-window implicit-GEMM conv.
// One block per (n, h-group of 4): out[n, 0:256, h0..h0+3, 0:64].
// LDS = 3-slot row ring [slot][wcol 0..65][c pad LC] (53,856 B, unchanged
// conflict-free layout). Steady state per output row:
//   issue 8 float4 global loads for row oh+2 (held in regs)   <- T14 issue-early
//   K-loop 36 chunks (A direct from global w/ 1-ahead prefetch,
//                     B ds_read_b128 from ring slots)          <- latency hides here
//   barrier; cvt+ds_write row oh+2 into retired slot; barrier  <- T14 write-late
//   epilogue stores row oh
// Staging traffic: 1 row (32 KB f32) per output row vs 3 rows before
// (x read 201 MB -> 98 MB); staging latency overlapped with MFMA.
// Grid 512 = 2 blocks/CU exactly, single round, no tail.
// ---------------------------------------------------------------------------
#define LC 136   // padded c dim: byte stride 272 => 16B-granule stride 17 ≡ 1 (mod 8)

__global__ __launch_bounds__(256, 2) void conv_mfma_kernel(
    const float* __restrict__ x, const unsigned short* __restrict__ wb,
    const float* __restrict__ bias, float* __restrict__ out) {
    __shared__ __align__(16) unsigned short xl[3 * 66 * LC];   // 53,856 B

    const int tid  = threadIdx.x;
    const int lane = tid & 63;
    const int wv   = tid >> 6;
    const int l15  = lane & 15;
    const int quad = lane >> 4;
    const int bid  = blockIdx.x;
    const int n    = bid >> 4;          // 32 n
    const int h0   = (bid & 15) << 2;   // 16 groups of 4 rows

    const int sw4  = tid & 15;          // staging: w-quad
    const int scg0 = tid >> 4;          // staging: c-quad base (0..15)

    // ---- zero halo columns (wcol 0 and 65) of all 3 slots ----
    if (tid < 96) {
        const int s   = tid >> 5;
        const int j   = tid & 31;
        const int col = (j >> 4) ? 65 : 0;
        const int c   = (j & 15) << 3;
        *(uint4*)(xl + (s * 66 + col) * LC + c) = make_uint4(0u, 0u, 0u, 0u);
    }

    // staged row held in registers between issue (pre-K-loop) and LDS write
    float4 st[2][4];

    auto stage_load = [&](int rimg) {
#pragma unroll
        for (int i = 0; i < 2; ++i) {
            const float4 z = make_float4(0.f, 0.f, 0.f, 0.f);
            st[i][0] = z; st[i][1] = z; st[i][2] = z; st[i][3] = z;
            if (rimg >= 0 && rimg < 64) {
                const int c = (scg0 + (i << 4)) << 2;
                const float4* gp = (const float4*)(x + (((n * 128 + c) * 64 + rimg) * 64) + (sw4 << 2));
                st[i][0] = gp[0];
                st[i][1] = gp[1024];   // +1 c-plane (64*64 floats)
                st[i][2] = gp[2048];
                st[i][3] = gp[3072];
            }
        }
    };

    auto stage_write = [&](int slot) {
#pragma unroll
        for (int i = 0; i < 2; ++i) {
            const int c = (scg0 + (i << 4)) << 2;
            unsigned short* base = xl + (slot * 66 + (sw4 << 2) + 1) * LC + c;
            *(ushort4*)(base)          = make_ushort4(f2bf(st[i][0].x), f2bf(st[i][1].x), f2bf(st[i][2].x), f2bf(st[i][3].x));
            *(ushort4*)(base + LC)     = make_ushort4(f2bf(st[i][0].y), f2bf(st[i][1].y), f2bf(st[i][2].y), f2bf(st[i][3].y));
            *(ushort4*)(base + 2 * LC) = make_ushort4(f2bf(st[i][0].z), f2bf(st[i][1].z), f2bf(st[i][2].z), f2bf(st[i][3].z));
            *(ushort4*)(base + 3 * LC) = make_ushort4(f2bf(st[i][0].w), f2bf(st[i][1].w), f2bf(st[i][2].w), f2bf(st[i][3].w));
        }
    };

    // ---- initial staging: rows h0-1, h0, h0+1 into slots (rimg+3)%3 ----
#pragma unroll 1
    for (int k = 0; k < 3; ++k) {
        const int rimg = h0 - 1 + k;
        stage_load(rimg);
        stage_write((rimg + 3) % 3);
    }
    __syncthreads();

    const int dwave = wv << 6;                       // 64 d per wave
    const bf16x8* wgv = (const bf16x8*)wb;           // 16 B granules
    const int abase = quad * 256 + dwave + l15;
    const unsigned short* bb = xl + l15 * LC + quad * 8;
    const float bv = bias[0];

    // prefetch A-frags for chunk 0 (persists across rows; chunk 35 wraps to 0)
    bf16x8 an[4];
#pragma unroll
    for (int dt = 0; dt < 4; ++dt) an[dt] = wgv[abase + dt * 16];

#pragma unroll 1
    for (int r = 0; r < 4; ++r) {
        const int oh = h0 + r;

        // issue next row's global loads; they complete under the K-loop
        if (r < 3) stage_load(oh + 2);

        f32x4 acc[4][4];
#pragma unroll
        for (int a0 = 0; a0 < 4; ++a0)
#pragma unroll
            for (int b0 = 0; b0 < 4; ++b0) acc[a0][b0] = (f32x4){0.f, 0.f, 0.f, 0.f};

#pragma unroll
        for (int tap = 0; tap < 9; ++tap) {
            const int kh = tap / 3;
            const int kw = tap - kh * 3;
            const int slot = (oh + 2 + kh) % 3;      // slot of image row oh-1+kh
            const unsigned short* bt = bb + (slot * 66 + kw) * LC;
#pragma unroll
            for (int c4 = 0; c4 < 4; ++c4) {
                const int ch = tap * 4 + c4;
                bf16x8 ac[4];
#pragma unroll
                for (int dt = 0; dt < 4; ++dt) ac[dt] = an[dt];
                const int nc = (ch + 1 == 36) ? 0 : ch + 1;   // wrap to chunk 0 for next row
                const bf16x8* g2 = wgv + nc * 1024 + abase;
#pragma unroll
                for (int dt = 0; dt < 4; ++dt) an[dt] = g2[dt * 16];
                const int c0 = c4 << 5;
                bf16x8 bfr[4];
                const unsigned short* bp = bt + c0;
#pragma unroll
                for (int pt = 0; pt < 4; ++pt) bfr[pt] = *(const bf16x8*)(bp + pt * 16 * LC);
#pragma unroll
                for (int dt = 0; dt < 4; ++dt)
#pragma unroll
                    for (int pt = 0; pt < 4; ++pt)
                        acc[dt][pt] = __builtin_amdgcn_mfma_f32_16x16x32_bf16(
                            ac[dt], bfr[pt], acc[dt][pt], 0, 0, 0);
            }
        }

        __syncthreads();                     // all waves done reading retired slot
        if (r < 3) stage_write((oh + 2) % 3);
        __syncthreads();                     // new row visible for next iteration

        // ---- epilogue: bias + store row oh. D layout: row(d)=quad*4+rr, col(w)=l15 ----
#pragma unroll
        for (int dt = 0; dt < 4; ++dt)
#pragma unroll
            for (int pt = 0; pt < 4; ++pt)
#pragma unroll
                for (int rr = 0; rr < 4; ++rr) {
                    const int d = dwave + dt * 16 + quad * 4 + rr;
                    const int w = pt * 16 + l15;
                    out[((n * 256 + d) * 64 + oh) * 64 + w] = acc[dt][pt][rr] + bv;
                }
    }
}

extern "C" void kernel_launch(void* const* d_in, const int* in_sizes, int n_in,
                              void* d_out, int out_size, void* d_ws, size_t ws_size,
                              hipStream_t stream) {
    const float* x     = (const float*)d_in[0];
    const float* core0 = (const float*)d_in[1];
    const float* core1 = (const float*)d_in[2];
    const float* core2 = (const float*)d_in[3];
    const float* bias  = (const float*)d_in[4];
    unsigned short* wb = (unsigned short*)d_ws;   // 1152*256*2 = 589,824 B

    build_w_kernel<<<256, 128, 0, stream>>>(core0, core1, core2, wb);
    conv_mfma_kernel<<<512, 256, 0, stream>>>(x, wb, bias, (float*)d_out);
}

// Round 2
// 382.234 us; speedup vs baseline: 1.2097x; 1.2097x over previous
//
#include <hip/hip_runtime.h>

typedef __bf16 bf16x8 __attribute__((ext_vector_type(8)));
typedef float f32x4 __attribute__((ext_vector_type(4)));

__device__ __forceinline__ unsigned short f2bf(float f) {
    union { float f; unsigned int u; } v; v.f = f;
    unsigned int u = v.u;
    unsigned int r = (u + 0x7fffu + ((u >> 16) & 1u)) >> 16;
    return (unsigned short)r;
}

// ---------------------------------------------------------------------------
// Kernel 1: reconstruct TT conv weights -> bf16, MFMA-A-fragment layout.
// kidx = (kh*3+kw)*128 + c ; stored wb[(kidx>>3)*2048 + d*8 + (kidx&7)]
// ---------------------------------------------------------------------------
__global__ void build_w_kernel(const float* __restrict__ core0,
                               const float* __restrict__ core1,
                               const float* __restrict__ core2,
                               unsigned short* __restrict__ wb) {
    __shared__ float s1[96];   // core1[d]: [r][kh][s]
    __shared__ float s2[12];   // core2[d]: [s][kw]
    const int d = blockIdx.x;
    const int c = threadIdx.x;   // 128 threads
    if (c < 96) s1[c] = core1[d * 96 + c];
    if (c >= 96 && c < 108) s2[c - 96] = core2[d * 12 + (c - 96)];
    __syncthreads();
    float t0[8];
#pragma unroll
    for (int r = 0; r < 8; ++r) t0[r] = core0[(d * 128 + c) * 8 + r];
#pragma unroll
    for (int kh = 0; kh < 3; ++kh) {
        float v[4] = {0.f, 0.f, 0.f, 0.f};
#pragma unroll
        for (int r = 0; r < 8; ++r)
#pragma unroll
            for (int s = 0; s < 4; ++s)
                v[s] += t0[r] * s1[(r * 3 + kh) * 4 + s];
#pragma unroll
        for (int kw = 0; kw < 3; ++kw) {
            float val = 0.f;
#pragma unroll
            for (int s = 0; s < 4; ++s) val += v[s] * s2[s * 3 + kw];
            const int kidx = (kh * 3 + kw) * 128 + c;
            wb[(kidx >> 3) * 2048 + d * 8 + (kidx & 7)] = f2bf(val);
        }
    }
}

// ---------------------------------------------------------------------------
// Kernel 2: implicit-GEMM conv, 2 output rows per block, ONE shared K-loop.
// Block (n, h-pair): out[n, 0:256, h0..h0+1, 0:64].  M=128 pixels, N=256 d,
// K=1152.  Stage 4 image rows (h0-1..h0+2) once as bf16 [slot][wcol][c pad
// LC=136] (71,808 B LDS -> 2 blocks/CU), ONE barrier.  K-loop: 36 chunks of
// {4 A-frags direct from global (L2-resident, 1-chunk-ahead prefetch) +
//  8 B-frag ds_read_b128 (both rows) + 32 MFMA} — each A-fetch now feeds 32
// MFMAs instead of 16: weight L2 traffic per output halves (1.18 -> 0.59 GB
// aggregate), A-load latency amortized 2x, staging redundancy 3x -> 2x.
// No register-held staging across the K-loop (round-1 spill lesson).
// ---------------------------------------------------------------------------
#define LC 136   // padded c dim: byte stride 272 => 16B-granule stride 17 ≡ 1 (mod 8)

__global__ __launch_bounds__(256, 2) void conv_mfma_kernel(
    const float* __restrict__ x, const unsigned short* __restrict__ wb,
    const float* __restrict__ bias, float* __restrict__ out) {
    __shared__ __align__(16) unsigned short xl[4 * 66 * LC];   // 71,808 B

    const int tid  = threadIdx.x;
    const int lane = tid & 63;
    const int wv   = tid >> 6;
    const int l15  = lane & 15;
    const int quad = lane >> 4;
    const int bid  = blockIdx.x;
    const int n    = bid >> 5;          // 32 n
    const int h0   = (bid & 31) << 1;   // 32 h-pairs

    // ---- zero halo columns (wcol 0 and 65) of all 4 slots ----
    if (tid < 128) {
        const int s   = tid >> 5;
        const int j   = tid & 31;
        const int col = (j >> 4) ? 65 : 0;
        const int c   = (j & 15) << 3;
        *(uint4*)(xl + (s * 66 + col) * LC + c) = make_uint4(0u, 0u, 0u, 0u);
    }

    // ---- stage image rows h0-1..h0+2 as bf16 [slot][wcol][c]; OOB -> zeros ----
#pragma unroll 2
    for (int i = 0; i < 8; ++i) {
        const int it  = tid + (i << 8);
        const int w4  = it & 15;
        const int cg  = (it >> 4) & 31;
        const int row = it >> 9;           // 0..3
        const int rimg = h0 + row - 1;
        float4 p0 = make_float4(0.f, 0.f, 0.f, 0.f), p1 = p0, p2 = p0, p3 = p0;
        const int c = cg << 2;
        const int w = w4 << 2;
        if (rimg >= 0 && rimg < 64) {
            const float4* gp = (const float4*)(x + (((n * 128 + c) * 64 + rimg) * 64 + w));
            p0 = gp[0];
            p1 = gp[1024];   // +1 c-plane (64*64 floats)
            p2 = gp[2048];
            p3 = gp[3072];
        }
        unsigned short* base = xl + (row * 66 + w + 1) * LC + c;
        *(ushort4*)(base)          = make_ushort4(f2bf(p0.x), f2bf(p1.x), f2bf(p2.x), f2bf(p3.x));
        *(ushort4*)(base + LC)     = make_ushort4(f2bf(p0.y), f2bf(p1.y), f2bf(p2.y), f2bf(p3.y));
        *(ushort4*)(base + 2 * LC) = make_ushort4(f2bf(p0.z), f2bf(p1.z), f2bf(p2.z), f2bf(p3.z));
        *(ushort4*)(base + 3 * LC) = make_ushort4(f2bf(p0.w), f2bf(p1.w), f2bf(p2.w), f2bf(p3.w));
    }
    __syncthreads();   // the ONLY barrier

    f32x4 acc0[4][4], acc1[4][4];
#pragma unroll
    for (int a0 = 0; a0 < 4; ++a0)
#pragma unroll
        for (int b0 = 0; b0 < 4; ++b0) {
            acc0[a0][b0] = (f32x4){0.f, 0.f, 0.f, 0.f};
            acc1[a0][b0] = (f32x4){0.f, 0.f, 0.f, 0.f};
        }

    const int dwave = wv << 6;                       // 64 d per wave
    const bf16x8* wgv = (const bf16x8*)wb;           // 16 B granules
    const int abase = quad * 256 + dwave + l15;      // lane's frag index within a chunk

    // prefetch A-frags for chunk 0
    bf16x8 an[4];
#pragma unroll
    for (int dt = 0; dt < 4; ++dt) an[dt] = wgv[abase + dt * 16];

    const unsigned short* bb = xl + l15 * LC + quad * 8;

#pragma unroll
    for (int tap = 0; tap < 9; ++tap) {
        const int kh = tap / 3;
        const int kw = tap - kh * 3;
#pragma unroll
        for (int c4 = 0; c4 < 4; ++c4) {
            const int ch = tap * 4 + c4;
            bf16x8 ac[4];
#pragma unroll
            for (int dt = 0; dt < 4; ++dt) ac[dt] = an[dt];
            if (ch + 1 < 36) {
                const bf16x8* g2 = wgv + (ch + 1) * 1024 + abase;
#pragma unroll
                for (int dt = 0; dt < 4; ++dt) an[dt] = g2[dt * 16];
            }
            const int c0 = c4 << 5;
            // B-frags: output row 0 uses image slots kh; row 1 uses kh+1
            bf16x8 bfr0[4], bfr1[4];
            const unsigned short* bp0 = bb + (kh * 66 + kw) * LC + c0;
#pragma unroll
            for (int pt = 0; pt < 4; ++pt) {
                bfr0[pt] = *(const bf16x8*)(bp0 + pt * 16 * LC);
                bfr1[pt] = *(const bf16x8*)(bp0 + 66 * LC + pt * 16 * LC);
            }
#pragma unroll
            for (int dt = 0; dt < 4; ++dt)
#pragma unroll
                for (int pt = 0; pt < 4; ++pt) {
                    acc0[dt][pt] = __builtin_amdgcn_mfma_f32_16x16x32_bf16(
                        ac[dt], bfr0[pt], acc0[dt][pt], 0, 0, 0);
                    acc1[dt][pt] = __builtin_amdgcn_mfma_f32_16x16x32_bf16(
                        ac[dt], bfr1[pt], acc1[dt][pt], 0, 0, 0);
                }
        }
    }

    // ---- epilogue: bias + store both rows. D layout: row(d)=quad*4+rr, col(w)=l15 ----
    const float bv = bias[0];
#pragma unroll
    for (int dt = 0; dt < 4; ++dt) {
#pragma unroll
        for (int pt = 0; pt < 4; ++pt) {
#pragma unroll
            for (int rr = 0; rr < 4; ++rr) {
                const int d = dwave + dt * 16 + quad * 4 + rr;
                const int w = pt * 16 + l15;
                out[((n * 256 + d) * 64 + h0) * 64 + w]     = acc0[dt][pt][rr] + bv;
                out[((n * 256 + d) * 64 + h0 + 1) * 64 + w] = acc1[dt][pt][rr] + bv;
            }
        }
    }
}

extern "C" void kernel_launch(void* const* d_in, const int* in_sizes, int n_in,
                              void* d_out, int out_size, void* d_ws, size_t ws_size,
                              hipStream_t stream) {
    const float* x     = (const float*)d_in[0];
    const float* core0 = (const float*)d_in[1];
    const float* core1 = (const float*)d_in[2];
    const float* core2 = (const float*)d_in[3];
    const float* bias  = (const float*)d_in[4];
    unsigned short* wb = (unsigned short*)d_ws;   // 1152*256*2 = 589,824 B

    build_w_kernel<<<256, 128, 0, stream>>>(core0, core1, core2, wb);
    conv_mfma_kernel<<<1024, 256, 0, stream>>>(x, wb, bias, (float*)d_out);
}

// Round 4
// 232.654 us; speedup vs baseline: 1.9875x; 1.6429x over previous
//
#include <hip/hip_runtime.h>

typedef __bf16 bf16x8 __attribute__((ext_vector_type(8)));
typedef float f32x4 __attribute__((ext_vector_type(4)));

__device__ __forceinline__ unsigned short f2bf(float f) {
    union { float f; unsigned int u; } v; v.f = f;
    unsigned int u = v.u;
    unsigned int r = (u + 0x7fffu + ((u >> 16) & 1u)) >> 16;
    return (unsigned short)r;
}

// ---------------------------------------------------------------------------
// Kernel 1: reconstruct TT conv weights -> bf16, MFMA-A-fragment layout.
// kidx = (kh*3+kw)*128 + c ; stored wb[(kidx>>3)*2048 + d*8 + (kidx&7)]
// ---------------------------------------------------------------------------
__global__ void build_w_kernel(const float* __restrict__ core0,
                               const float* __restrict__ core1,
                               const float* __restrict__ core2,
                               unsigned short* __restrict__ wb) {
    __shared__ float s1[96];   // core1[d]: [r][kh][s]
    __shared__ float s2[12];   // core2[d]: [s][kw]
    const int d = blockIdx.x;
    const int c = threadIdx.x;   // 128 threads
    if (c < 96) s1[c] = core1[d * 96 + c];
    if (c >= 96 && c < 108) s2[c - 96] = core2[d * 12 + (c - 96)];
    __syncthreads();
    float t0[8];
#pragma unroll
    for (int r = 0; r < 8; ++r) t0[r] = core0[(d * 128 + c) * 8 + r];
#pragma unroll
    for (int kh = 0; kh < 3; ++kh) {
        float v[4] = {0.f, 0.f, 0.f, 0.f};
#pragma unroll
        for (int r = 0; r < 8; ++r)
#pragma unroll
            for (int s = 0; s < 4; ++s)
                v[s] += t0[r] * s1[(r * 3 + kh) * 4 + s];
#pragma unroll
        for (int kw = 0; kw < 3; ++kw) {
            float val = 0.f;
#pragma unroll
            for (int s = 0; s < 4; ++s) val += v[s] * s2[s * 3 + kw];
            const int kidx = (kh * 3 + kw) * 128 + c;
            wb[(kidx >> 3) * 2048 + d * 8 + (kidx & 7)] = f2bf(val);
        }
    }
}

// ---------------------------------------------------------------------------
// Kernel 2: implicit-GEMM conv, 512 threads / 8 waves, wave-row-split.
// Block (n, h-pair): out[n, 0:256, h0..h0+1, 0:64].
// Waves 0-3 compute row h0 (64 d each); waves 4-7 compute row h0+1.
// PER-WAVE state is EXACTLY the round-0 68-VGPR shape: acc[4][4] + an[4] +
// bfr[4] — no acc doubling (rounds 1-2 spilled with 2x acc: VGPR 128,
// WRITE_SIZE 368-513 MB of scratch; that signature must not reappear).
// Stage 4 image rows (h0-1..h0+2) once as bf16 [slot][wcol][c pad LC=136]
// (71,808 B -> 2 blocks/CU = 16 waves/CU vs round-0's 12), ONE barrier.
// Gains vs round 0: staging redundancy 3x->2x (x reads 201->134 MB),
// +33% waves for latency hiding, 2nd wave-group's A-loads hit L1.
// ---------------------------------------------------------------------------
#define LC 136   // padded c dim: byte stride 272 => 16B-granule stride 17 ≡ 1 (mod 8)

__global__ __launch_bounds__(512, 2) void conv_mfma_kernel(
    const float* __restrict__ x, const unsigned short* __restrict__ wb,
    const float* __restrict__ bias, float* __restrict__ out) {
    __shared__ __align__(16) unsigned short xl[4 * 66 * LC];   // 71,808 B

    const int tid  = threadIdx.x;
    const int lane = tid & 63;
    const int wv   = tid >> 6;          // 0..7
    const int l15  = lane & 15;
    const int quad = lane >> 4;
    const int bid  = blockIdx.x;
    const int n    = bid >> 5;          // 32 n
    const int h0   = (bid & 31) << 1;   // 32 h-pairs
    const int rowsel = wv >> 2;         // 0: row h0, 1: row h0+1

    // ---- zero halo columns (wcol 0 and 65) of all 4 slots ----
    if (tid < 128) {
        const int s   = tid >> 5;
        const int j   = tid & 31;
        const int col = (j >> 4) ? 65 : 0;
        const int c   = (j & 15) << 3;
        *(uint4*)(xl + (s * 66 + col) * LC + c) = make_uint4(0u, 0u, 0u, 0u);
    }

    // ---- stage image rows h0-1..h0+2 as bf16 [slot][wcol][c]; OOB -> zeros ----
#pragma unroll 2
    for (int i = 0; i < 4; ++i) {
        const int it  = tid + (i << 9);
        const int w4  = it & 15;
        const int cg  = (it >> 4) & 31;
        const int row = it >> 9;           // 0..3
        const int rimg = h0 + row - 1;
        float4 p0 = make_float4(0.f, 0.f, 0.f, 0.f), p1 = p0, p2 = p0, p3 = p0;
        const int c = cg << 2;
        const int w = w4 << 2;
        if (rimg >= 0 && rimg < 64) {
            const float4* gp = (const float4*)(x + (((n * 128 + c) * 64 + rimg) * 64 + w));
            p0 = gp[0];
            p1 = gp[1024];   // +1 c-plane (64*64 floats)
            p2 = gp[2048];
            p3 = gp[3072];
        }
        unsigned short* base = xl + (row * 66 + w + 1) * LC + c;
        *(ushort4*)(base)          = make_ushort4(f2bf(p0.x), f2bf(p1.x), f2bf(p2.x), f2bf(p3.x));
        *(ushort4*)(base + LC)     = make_ushort4(f2bf(p0.y), f2bf(p1.y), f2bf(p2.y), f2bf(p3.y));
        *(ushort4*)(base + 2 * LC) = make_ushort4(f2bf(p0.z), f2bf(p1.z), f2bf(p2.z), f2bf(p3.z));
        *(ushort4*)(base + 3 * LC) = make_ushort4(f2bf(p0.w), f2bf(p1.w), f2bf(p2.w), f2bf(p3.w));
    }
    __syncthreads();   // the ONLY barrier

    f32x4 acc[4][4];
#pragma unroll
    for (int a0 = 0; a0 < 4; ++a0)
#pragma unroll
        for (int b0 = 0; b0 < 4; ++b0) acc[a0][b0] = (f32x4){0.f, 0.f, 0.f, 0.f};

    const int dwave = (wv & 3) << 6;                 // 64 d per wave
    const bf16x8* wgv = (const bf16x8*)wb;           // 16 B granules
    const int abase = quad * 256 + dwave + l15;      // lane's frag index within a chunk

    // prefetch A-frags for chunk 0
    bf16x8 an[4];
#pragma unroll
    for (int dt = 0; dt < 4; ++dt) an[dt] = wgv[abase + dt * 16];

    // B base: rowsel picks the wave's image-row window (slots rowsel..rowsel+2)
    const unsigned short* bb = xl + (rowsel * 66 + l15) * LC + quad * 8;

#pragma unroll
    for (int tap = 0; tap < 9; ++tap) {
        const int kh = tap / 3;
        const int kw = tap - kh * 3;
#pragma unroll
        for (int c4 = 0; c4 < 4; ++c4) {
            const int ch = tap * 4 + c4;
            bf16x8 ac[4];
#pragma unroll
            for (int dt = 0; dt < 4; ++dt) ac[dt] = an[dt];
            if (ch + 1 < 36) {
                const bf16x8* g2 = wgv + (ch + 1) * 1024 + abase;
#pragma unroll
                for (int dt = 0; dt < 4; ++dt) an[dt] = g2[dt * 16];
            }
            const int c0 = c4 << 5;
            bf16x8 bfr[4];
            const unsigned short* bp = bb + (kh * 66 + kw) * LC + c0;
#pragma unroll
            for (int pt = 0; pt < 4; ++pt) bfr[pt] = *(const bf16x8*)(bp + pt * 16 * LC);
#pragma unroll
            for (int dt = 0; dt < 4; ++dt)
#pragma unroll
                for (int pt = 0; pt < 4; ++pt)
                    acc[dt][pt] = __builtin_amdgcn_mfma_f32_16x16x32_bf16(
                        ac[dt], bfr[pt], acc[dt][pt], 0, 0, 0);
        }
    }

    // ---- epilogue: bias + store. D layout: row(d)=quad*4+rr, col(w)=l15 ----
    const float bv = bias[0];
    const int oh = h0 + rowsel;
#pragma unroll
    for (int dt = 0; dt < 4; ++dt) {
#pragma unroll
        for (int pt = 0; pt < 4; ++pt) {
#pragma unroll
            for (int rr = 0; rr < 4; ++rr) {
                const int d = dwave + dt * 16 + quad * 4 + rr;
                const int w = pt * 16 + l15;
                out[((n * 256 + d) * 64 + oh) * 64 + w] = acc[dt][pt][rr] + bv;
            }
        }
    }
}

extern "C" void kernel_launch(void* const* d_in, const int* in_sizes, int n_in,
                              void* d_out, int out_size, void* d_ws, size_t ws_size,
                              hipStream_t stream) {
    const float* x     = (const float*)d_in[0];
    const float* core0 = (const float*)d_in[1];
    const float* core1 = (const float*)d_in[2];
    const float* core2 = (const float*)d_in[3];
    const float* bias  = (const float*)d_in[4];
    unsigned short* wb = (unsigned short*)d_ws;   // 1152*256*2 = 589,824 B

    build_w_kernel<<<256, 128, 0, stream>>>(core0, core1, core2, wb);
    conv_mfma_kernel<<<1024, 512, 0, stream>>>(x, wb, bias, (float*)d_out);
}